// Round 4
// baseline (105.409 us; speedup 1.0000x reference)
//
#include <hip/hip_runtime.h>
#include <hip/hip_bf16.h>

#define LP   640
#define LC   128
#define NODE 128
#define HID  32
#define PAIR 128
#define EPS  1e-5f

typedef __bf16 bf16_t;
typedef __attribute__((ext_vector_type(8))) __bf16 bf16x8;
typedef __attribute__((ext_vector_type(4))) float f32x4;

// ---------------- K1: wave-per-row LayerNorm + projection, plus mask output ----------------
// blocks 0..191: 4 rows each (rows 0..639 = p, 640..767 = c)
// blocks 192..271: mask writes (1024 elems each, float4)
__global__ __launch_bounds__(256) void k1_rows(
    const float* __restrict__ p_embed, const float* __restrict__ c_embed,
    const int* __restrict__ p_mask, const int* __restrict__ c_mask,
    const float* __restrict__ ln_p_w, const float* __restrict__ ln_p_b,
    const float* __restrict__ ln_c_w, const float* __restrict__ ln_c_b,
    const float* __restrict__ W_p, const float* __restrict__ b_p,
    const float* __restrict__ W_c, const float* __restrict__ b_c,
    bf16_t* __restrict__ p_out, bf16_t* __restrict__ c_out,
    float* __restrict__ mask_out)
{
    const int blk = blockIdx.x;
    const int t = threadIdx.x;

    if (blk >= 192) {
        // mask blocks: 80 blocks x 1024 elems = 81920 = LP*LC
        int idx = (blk - 192) * 1024 + t * 4;
        int i = idx >> 7, j = idx & 127;
        float pm = (p_mask[i] != 0) ? 1.0f : 0.0f;
        f32x4 m;
        m[0] = pm * ((c_mask[j + 0] != 0) ? 1.0f : 0.0f);
        m[1] = pm * ((c_mask[j + 1] != 0) ? 1.0f : 0.0f);
        m[2] = pm * ((c_mask[j + 2] != 0) ? 1.0f : 0.0f);
        m[3] = pm * ((c_mask[j + 3] != 0) ? 1.0f : 0.0f);
        *(f32x4*)(mask_out + idx) = m;
        return;
    }

    const int wave = t >> 6;
    const int lane = t & 63;
    const int row = blk * 4 + wave;       // 0..767

    const float* x; const float* lw; const float* lb;
    const float* W; const float* bb; bf16_t* yo;
    if (row < LP) {
        x = p_embed + row * NODE; lw = ln_p_w; lb = ln_p_b;
        W = W_p; bb = b_p; yo = p_out + row * HID;
    } else {
        int r = row - LP;
        x = c_embed + r * NODE; lw = ln_c_w; lb = ln_c_b;
        W = W_c; bb = b_c; yo = c_out + r * HID;
    }

    __shared__ __align__(16) float sx[4][NODE];

    // LayerNorm: 2 elems/lane, fused sum+sumsq shuffle reduction
    float v0 = x[lane], v1 = x[lane + 64];
    float s  = v0 + v1;
    float ss = v0 * v0 + v1 * v1;
    #pragma unroll
    for (int off = 32; off > 0; off >>= 1) {
        s  += __shfl_xor(s, off);
        ss += __shfl_xor(ss, off);
    }
    float mean = s * (1.0f / NODE);
    float var  = ss * (1.0f / NODE) - mean * mean;
    float rs   = rsqrtf(var + EPS);
    sx[wave][lane]      = (v0 - mean) * rs * lw[lane]      + lb[lane];
    sx[wave][lane + 64] = (v1 - mean) * rs * lw[lane + 64] + lb[lane + 64];
    __syncthreads();

    // projection: lane = half*32 + h; dot over 64 c's, then combine halves
    const int h = lane & 31, half = lane >> 5;
    const f32x4* wv = (const f32x4*)(W + h * NODE + half * 64);
    const f32x4* xv = (const f32x4*)(&sx[wave][half * 64]);
    float acc = 0.f;
    #pragma unroll
    for (int z = 0; z < 16; ++z) {
        f32x4 a = wv[z], b = xv[z];
        acc += a[0]*b[0] + a[1]*b[1] + a[2]*b[2] + a[3]*b[3];
    }
    acc += __shfl_xor(acc, 32);
    if (lane < 32) yo[h] = (bf16_t)(acc + bb[h]);
}

// ---------------- K2: S2[n = j*128+k][c] = sum_e c[j,e] * W3[k,c,e], bf16 out ----------------
// 512 blocks x 64 thr: block b -> k = b>>2, mt pair (b&3)*2.
__global__ __launch_bounds__(64) void k2_s(
    const bf16_t* __restrict__ c_b, const float* __restrict__ W_out,
    bf16_t* __restrict__ S2)
{
    const int k = blockIdx.x >> 2;
    const int mtbase = (blockIdx.x & 3) * 2;
    const int lane = threadIdx.x;
    const int q = lane >> 4, l16 = lane & 15;
    const float* Wrow = W_out + k * (HID * HID);

    f32x4 zacc = {0.f, 0.f, 0.f, 0.f};

    // B fragments: B[e][c] from W3[k][c][e] stored [c][e]-row-major
    bf16x8 bfrag[2];
    #pragma unroll
    for (int nt = 0; nt < 2; ++nt) {
        int c = nt * 16 + l16;
        const float* wp = Wrow + c * 32 + q * 8;
        f32x4 w0 = *(const f32x4*)(wp);
        f32x4 w1 = *(const f32x4*)(wp + 4);
        bf16x8 bf;
        #pragma unroll
        for (int z = 0; z < 4; ++z) { bf[z] = (bf16_t)w0[z]; bf[z + 4] = (bf16_t)w1[z]; }
        bfrag[nt] = bf;
    }

    #pragma unroll
    for (int mi = 0; mi < 2; ++mi) {
        int mt = mtbase + mi;
        bf16x8 afrag = *(const bf16x8*)(c_b + (mt * 16 + l16) * 32 + q * 8);
        f32x4 acc0 = __builtin_amdgcn_mfma_f32_16x16x32_bf16(afrag, bfrag[0], zacc, 0, 0, 0);
        f32x4 acc1 = __builtin_amdgcn_mfma_f32_16x16x32_bf16(afrag, bfrag[1], zacc, 0, 0, 0);
        #pragma unroll
        for (int r = 0; r < 4; ++r) {
            int jrow = mt * 16 + q * 4 + r;
            S2[(jrow * 128 + k) * 32 + l16]      = (bf16_t)acc0[r];
            S2[(jrow * 128 + k) * 32 + 16 + l16] = (bf16_t)acc1[r];
        }
    }
}

// ---------------- K3: out[i, n] = sum_c p[i,c] * S2[n][c], + b_out, masked ----------------
// 1280 blocks x 256 thr; block tile 64i x 128n (one j per block); wave tile 16i x 128n.
// Operand-swapped MFMA: A = S2 rows (M dim = n), B = p rows (N dim = i).
// C layout: col(lane&15) = i, row(q*4+reg) = n -> each lane holds 4 consecutive n
// => one global_store_dwordx4 per tile per lane (16 B/lane coalesced stores).
__global__ __launch_bounds__(256) void k3_main(
    const bf16_t* __restrict__ p_b, const bf16_t* __restrict__ S2,
    const float* __restrict__ b_out,
    const int* __restrict__ p_mask, const int* __restrict__ c_mask,
    float* __restrict__ out)
{
    const int blk = blockIdx.x;
    const int bn = blk & 127;   // 128 n-tiles of 128 (== j)
    const int bi = blk >> 7;    // 10 i-tiles of 64
    const int wave = threadIdx.x >> 6;
    const int lane = threadIdx.x & 63;
    const int q = lane >> 4, l16 = lane & 15;
    const int i0 = bi * 64 + wave * 16;
    const int n0 = bn * 128;

    f32x4 zacc = {0.f, 0.f, 0.f, 0.f};

    // B fragment (N dim = i): p row per l16, loaded once per wave
    bf16x8 bfrag = *(const bf16x8*)(p_b + (i0 + l16) * 32 + q * 8);

    f32x4 acc[8];
    #pragma unroll
    for (int t = 0; t < 8; ++t) {
        // A fragment (M dim = n): S2 row n0 + t*16 + l16
        bf16x8 afrag = *(const bf16x8*)(S2 + (n0 + t * 16 + l16) * 32 + q * 8);
        acc[t] = __builtin_amdgcn_mfma_f32_16x16x32_bf16(afrag, bfrag, zacc, 0, 0, 0);
    }

    // epilogue: j uniform per block; per-lane i = i0 + l16
    const int i = i0 + l16;
    const float pm = (((p_mask[i] != 0) && (c_mask[bn] != 0)) ? 1.f : 0.f);
    float* orow = out + (size_t)i * (LC * PAIR) + n0;

    #pragma unroll
    for (int t = 0; t < 8; ++t) {
        // lane holds n = n0 + t*16 + q*4 + r, r=0..3 (consecutive)
        f32x4 bo = *(const f32x4*)(b_out + t * 16 + q * 4);
        f32x4 v;
        #pragma unroll
        for (int r = 0; r < 4; ++r) v[r] = (acc[t][r] + bo[r]) * pm;
        *(f32x4*)(orow + t * 16 + q * 4) = v;
    }
}

extern "C" void kernel_launch(void* const* d_in, const int* in_sizes, int n_in,
                              void* d_out, int out_size, void* d_ws, size_t ws_size,
                              hipStream_t stream) {
    const float* p_embed = (const float*)d_in[0];
    const float* c_embed = (const float*)d_in[1];
    const int* p_mask = (const int*)d_in[2];
    const int* c_mask = (const int*)d_in[3];
    const float* ln_p_w = (const float*)d_in[4];
    const float* ln_p_b = (const float*)d_in[5];
    const float* ln_c_w = (const float*)d_in[6];
    const float* ln_c_b = (const float*)d_in[7];
    const float* W_p   = (const float*)d_in[8];
    const float* b_p   = (const float*)d_in[9];
    const float* W_c   = (const float*)d_in[10];
    const float* b_c   = (const float*)d_in[11];
    const float* W_out = (const float*)d_in[12];
    const float* b_out = (const float*)d_in[13];

    // workspace layout
    bf16_t* p_b = (bf16_t*)d_ws;                              // 640*32*2  = 40960 B
    bf16_t* c_b = (bf16_t*)((char*)d_ws + 40960);             // 128*32*2  = 8192 B
    bf16_t* S2  = (bf16_t*)((char*)d_ws + 49152);             // 16384*32*2 = 1 MiB

    float* out = (float*)d_out;
    float* mask_out = out + (size_t)LP * LC * PAIR;           // tuple output #2

    k1_rows<<<272, 256, 0, stream>>>(
        p_embed, c_embed, p_mask, c_mask,
        ln_p_w, ln_p_b, ln_c_w, ln_c_b,
        W_p, b_p, W_c, b_c, p_b, c_b, mask_out);

    k2_s<<<512, 64, 0, stream>>>(c_b, W_out, S2);

    k3_main<<<1280, 256, 0, stream>>>(p_b, S2, b_out, p_mask, c_mask, out);
}